// Round 2
// baseline (935.242 us; speedup 1.0000x reference)
//
#include <hip/hip_runtime.h>
#include <hip/hip_bf16.h>

// ---------------------------------------------------------------------------
// EdgeClassifier: 2x GCNConv + edge MLP. All f32.
// Pipeline:
//   0. memset degcnt/cursor
//   1. hist: indeg per dst
//   2. dinv = rsqrt(indeg+1)
//   3. scan -> row_start (CSR by dst)
//   4. scatter -> col[] (src indices per dst row)
//   5. hscA = (x @ W1) * dinv          (bufA, aliased onto d_out)
//   6. h1 = relu(dinv * (self + gather(hscA)) + b1)   -> bufB
//   7. hscA = (h1 @ W2) * dinv         -> bufA
//   8. h2 = dinv * (self + gather(hscA)) + b2         -> bufB
//   9. edge MLP: relu([h2[s],h2[d],attr] @ Wc1 + bc1) @ Wc2 + bc2 -> d_out
// bufA aliases d_out: last read of bufA is step 8; step 9 reads only bufB.
// ---------------------------------------------------------------------------

__global__ __launch_bounds__(256) void k_hist(const int* __restrict__ ei, int* __restrict__ degcnt, int E)
{
    int e = blockIdx.x * 256 + threadIdx.x;
    if (e < E) atomicAdd(&degcnt[ei[E + e]], 1);   // dst row of edge_index
}

__global__ __launch_bounds__(256) void k_dinv(const int* __restrict__ degcnt, float* __restrict__ dinv, int n)
{
    int v = blockIdx.x * 256 + threadIdx.x;
    if (v < n) dinv[v] = rsqrtf((float)(degcnt[v] + 1));   // +1 self loop
}

__global__ __launch_bounds__(256) void k_bsum(const int* __restrict__ deg, int n, int* __restrict__ bsum)
{
    __shared__ int s[256];
    int t = threadIdx.x;
    int i = blockIdx.x * 256 + t;
    s[t] = (i < n) ? deg[i] : 0;
    __syncthreads();
    for (int o = 128; o > 0; o >>= 1) {
        if (t < o) s[t] += s[t + o];
        __syncthreads();
    }
    if (t == 0) bsum[blockIdx.x] = s[0];
}

__global__ __launch_bounds__(512) void k_boff(const int* __restrict__ bsum, int nb, int* __restrict__ boff)
{
    __shared__ int s[512];
    int t = threadIdx.x;
    int v = (t < nb) ? bsum[t] : 0;
    s[t] = v;
    __syncthreads();
    for (int o = 1; o < 512; o <<= 1) {
        int a = (t >= o) ? s[t - o] : 0;
        __syncthreads();
        s[t] += a;
        __syncthreads();
    }
    if (t < nb) boff[t] = s[t] - v;   // exclusive
}

__global__ __launch_bounds__(256) void k_rowstart(const int* __restrict__ deg, const int* __restrict__ boff,
                                                  int* __restrict__ rs, int n, int total)
{
    __shared__ int s[256];
    int t = threadIdx.x;
    int i = blockIdx.x * 256 + t;
    int v = (i < n) ? deg[i] : 0;
    s[t] = v;
    __syncthreads();
    for (int o = 1; o < 256; o <<= 1) {
        int a = (t >= o) ? s[t - o] : 0;
        __syncthreads();
        s[t] += a;
        __syncthreads();
    }
    if (i < n) rs[i] = boff[blockIdx.x] + s[t] - v;
    if (i == 0) rs[n] = total;
}

__global__ __launch_bounds__(256) void k_scatter(const int* __restrict__ ei, const int* __restrict__ rs,
                                                 int* __restrict__ cursor, int* __restrict__ col, int E)
{
    int e = blockIdx.x * 256 + threadIdx.x;
    if (e < E) {
        int d = ei[E + e];
        int pos = atomicAdd(&cursor[d], 1);
        col[rs[d] + pos] = ei[e];
    }
}

// hsc[v][j] = dinv[v] * sum_k in[v][k] * W[k][j]   (wave-per-node, lane=j)
template <int DIN>
__global__ __launch_bounds__(256) void k_nodemm(const float* __restrict__ in, const float* __restrict__ W,
                                                const float* __restrict__ dinv, float* __restrict__ out, int n)
{
    int lane = threadIdx.x & 63;
    int v = __builtin_amdgcn_readfirstlane(blockIdx.x * 4 + (threadIdx.x >> 6));
    if (v >= n) return;
    const float* row = &in[(size_t)v * DIN];   // wave-uniform -> scalar loads
    float acc = 0.f;
#pragma unroll
    for (int k = 0; k < DIN; ++k) acc = fmaf(row[k], W[k * 64 + lane], acc);
    out[(size_t)v * 64 + lane] = acc * dinv[v];
}

// out[v][j] = f( dinv[v] * (hsc[v][j] + sum_{e: dst=v} hsc[col[e]][j]) + bias[j] )
__global__ __launch_bounds__(256) void k_agg(const float* __restrict__ hsc, const float* __restrict__ dinv,
                                             const int* __restrict__ rs, const int* __restrict__ col,
                                             const float* __restrict__ bias, float* __restrict__ out,
                                             int n, int do_relu)
{
    int lane = threadIdx.x & 63;
    int v = __builtin_amdgcn_readfirstlane(blockIdx.x * 4 + (threadIdx.x >> 6));
    if (v >= n) return;
    float acc = hsc[(size_t)v * 64 + lane];   // self loop
    int i = rs[v], end = rs[v + 1];
    for (; i + 3 < end; i += 4) {
        int s0 = col[i], s1 = col[i + 1], s2 = col[i + 2], s3 = col[i + 3];
        float a0 = hsc[(size_t)s0 * 64 + lane];
        float a1 = hsc[(size_t)s1 * 64 + lane];
        float a2 = hsc[(size_t)s2 * 64 + lane];
        float a3 = hsc[(size_t)s3 * 64 + lane];
        acc += a0; acc += a1; acc += a2; acc += a3;
    }
    for (; i < end; ++i) acc += hsc[(size_t)col[i] * 64 + lane];
    float r = dinv[v] * acc + bias[lane];
    if (do_relu) r = r > 0.f ? r : 0.f;
    out[(size_t)v * 64 + lane] = r;
}

// Edge MLP: 64 edges per block. ef tile staged in LDS; Wc1/bc1/Wc2 via scalar loads.
#define EF_PAD 148   // 144 features, padded, multiple of 4 for float4 alignment

__global__ __launch_bounds__(256, 3) void k_edge_mlp(const float* __restrict__ h2, const float* __restrict__ eattr,
                                                     const int* __restrict__ ei,
                                                     const float* __restrict__ Wc1, const float* __restrict__ bc1,
                                                     const float* __restrict__ Wc2, const float* __restrict__ bc2,
                                                     float* __restrict__ out, int E)
{
    __shared__ float ef[64 * EF_PAD];        // ~37 KB
    __shared__ float part[4 * 64 * 5];       // 5 KB
    const int tid = threadIdx.x;
    const long e0 = (long)blockIdx.x * 64;

    // ---- stage ef tile: [h2[src] (64) | h2[dst] (64) | attr (16)] per edge ----
#pragma unroll
    for (int it = 0; it < 9; ++it) {
        int id = it * 256 + tid;          // 0..2303 = 64 edges * 36 float4-chunks
        int e = id / 36;
        int kc = id - e * 36;
        long edge = e0 + e;
        if (edge >= E) edge = E - 1;      // clamp (garbage tail, never written out)
        float4 v;
        if (kc < 16) {
            int s = ei[edge];
            v = *(const float4*)&h2[(size_t)s * 64 + kc * 4];
        } else if (kc < 32) {
            int d = ei[E + edge];
            v = *(const float4*)&h2[(size_t)d * 64 + (kc - 16) * 4];
        } else {
            v = *(const float4*)&eattr[(size_t)edge * 16 + (kc - 32) * 4];
        }
        *(float4*)&ef[e * EF_PAD + kc * 4] = v;
    }
    __syncthreads();

    // ---- compute: thread = (edge=lane, 16-hidden-group=wave) ----
    const int lane = tid & 63;
    const int j0 = __builtin_amdgcn_readfirstlane((tid >> 6) * 16);   // wave-uniform

    float acc[16];
#pragma unroll
    for (int jj = 0; jj < 16; ++jj) acc[jj] = 0.f;

    const float* efrow = &ef[lane * EF_PAD];
    for (int kc = 0; kc < 36; ++kc) {
        float4 ev = *(const float4*)&efrow[kc * 4];
#pragma unroll
        for (int d = 0; d < 4; ++d) {
            const float* w = &Wc1[(kc * 4 + d) * 64 + j0];   // uniform -> s_load
            float xv = (&ev.x)[d];
#pragma unroll
            for (int jj = 0; jj < 16; ++jj) acc[jj] = fmaf(xv, w[jj], acc[jj]);
        }
    }

    // ---- layer 2 partials ----
    float p[5];
#pragma unroll
    for (int c = 0; c < 5; ++c) p[c] = 0.f;
#pragma unroll
    for (int jj = 0; jj < 16; ++jj) {
        float hid = acc[jj] + bc1[j0 + jj];
        hid = hid > 0.f ? hid : 0.f;
#pragma unroll
        for (int c = 0; c < 5; ++c) p[c] = fmaf(hid, Wc2[(j0 + jj) * 5 + c], p[c]);
    }
    const int jg = tid >> 6;
#pragma unroll
    for (int c = 0; c < 5; ++c) part[(jg * 64 + lane) * 5 + c] = p[c];
    __syncthreads();

    // ---- reduce 4 groups, add bc2, write out ----
    // 320 work items (64 edges x 5 classes) over 256 threads: grid-stride.
    for (int t = tid; t < 320; t += 256) {
        int e = t / 5;
        int c = t - 5 * e;
        if (e0 + e < E) {
            float o = bc2[c];
#pragma unroll
            for (int g = 0; g < 4; ++g) o += part[(g * 64 + e) * 5 + c];
            out[(size_t)(e0 + e) * 5 + c] = o;
        }
    }
}

extern "C" void kernel_launch(void* const* d_in, const int* in_sizes, int n_in,
                              void* d_out, int out_size, void* d_ws, size_t ws_size,
                              hipStream_t stream)
{
    const float* x     = (const float*)d_in[0];
    const int*   ei    = (const int*)d_in[1];
    const float* eattr = (const float*)d_in[2];
    const float* W1    = (const float*)d_in[3];
    const float* b1    = (const float*)d_in[4];
    const float* W2    = (const float*)d_in[5];
    const float* b2    = (const float*)d_in[6];
    const float* Wc1   = (const float*)d_in[7];
    const float* bc1   = (const float*)d_in[8];
    const float* Wc2   = (const float*)d_in[9];
    const float* bc2   = (const float*)d_in[10];
    float* outp = (float*)d_out;

    const int N = in_sizes[0] / 32;
    const int E = in_sizes[1] / 2;

    // ---- carve workspace ----
    size_t off = 0;
    char* base = (char*)d_ws;
    auto carve = [&](size_t bytes) -> void* {
        void* p = base + off;
        off += (bytes + 255) & ~(size_t)255;
        return p;
    };
    int*   degcnt = (int*)carve((size_t)2 * N * 4);   // degcnt + cursor adjacent
    int*   cursor = degcnt + N;
    float* dinv   = (float*)carve((size_t)N * 4);
    int*   rs     = (int*)carve((size_t)(N + 1) * 4);
    int*   bsum   = (int*)carve(512 * 4);
    int*   boff   = (int*)carve(512 * 4);
    int*   col    = (int*)carve((size_t)E * 4);
    float* bufB   = (float*)carve((size_t)N * 64 * 4);
    float* bufA   = outp;   // alias: dead before edge MLP writes d_out
    (void)ws_size; (void)n_in; (void)out_size;

    const int NB = (N + 255) / 256;
    const int EB = (E + 255) / 256;
    const int NV = (N + 3) / 4;        // wave-per-node kernels, 4 nodes/block
    const int MB = (int)((E + 63) / 64);

    hipMemsetAsync(degcnt, 0, (size_t)2 * N * 4, stream);

    k_hist<<<EB, 256, 0, stream>>>(ei, degcnt, E);
    k_dinv<<<NB, 256, 0, stream>>>(degcnt, dinv, N);
    k_bsum<<<NB, 256, 0, stream>>>(degcnt, N, bsum);
    k_boff<<<1, 512, 0, stream>>>(bsum, NB, boff);
    k_rowstart<<<NB, 256, 0, stream>>>(degcnt, boff, rs, N, E);
    k_scatter<<<EB, 256, 0, stream>>>(ei, rs, cursor, col, E);

    // layer 1
    k_nodemm<32><<<NV, 256, 0, stream>>>(x, W1, dinv, bufA, N);
    k_agg<<<NV, 256, 0, stream>>>(bufA, dinv, rs, col, b1, bufB, N, 1);
    // layer 2
    k_nodemm<64><<<NV, 256, 0, stream>>>(bufB, W2, dinv, bufA, N);
    k_agg<<<NV, 256, 0, stream>>>(bufA, dinv, rs, col, b2, bufB, N, 0);
    // edge MLP
    k_edge_mlp<<<MB, 256, 0, stream>>>(bufB, eattr, ei, Wc1, bc1, Wc2, bc2, outp, E);
}

// Round 3
// 517.989 us; speedup vs baseline: 1.8055x; 1.8055x over previous
//
#include <hip/hip_runtime.h>
#include <hip/hip_bf16.h>

// ---------------------------------------------------------------------------
// EdgeClassifier: 2x GCNConv + edge MLP.
//   CSR build (hist/scan/scatter) -> 2x (nodemm + agg) -> MFMA edge MLP.
// Edge MLP: layer1 [E,144]@[144,64] via mfma_f32_32x32x16_bf16 (f32 accum),
// layer2 [E,64]@[64,5] via f32 VALU dots from LDS.
// ---------------------------------------------------------------------------

typedef __attribute__((ext_vector_type(8))) short  bf16x8;
typedef __attribute__((ext_vector_type(16))) float f32x16;

__device__ inline short f2bf(float f)
{
    union { float f; unsigned u; } v; v.f = f;
    unsigned r = v.u + 0x7fff + ((v.u >> 16) & 1);   // RNE
    return (short)(r >> 16);
}

__global__ __launch_bounds__(256) void k_hist(const int* __restrict__ ei, int* __restrict__ degcnt, int E)
{
    int e = blockIdx.x * 256 + threadIdx.x;
    if (e < E) atomicAdd(&degcnt[ei[E + e]], 1);   // dst row of edge_index
}

__global__ __launch_bounds__(256) void k_dinv(const int* __restrict__ degcnt, float* __restrict__ dinv, int n)
{
    int v = blockIdx.x * 256 + threadIdx.x;
    if (v < n) dinv[v] = rsqrtf((float)(degcnt[v] + 1));   // +1 self loop
}

__global__ __launch_bounds__(256) void k_bsum(const int* __restrict__ deg, int n, int* __restrict__ bsum)
{
    __shared__ int s[256];
    int t = threadIdx.x;
    int i = blockIdx.x * 256 + t;
    s[t] = (i < n) ? deg[i] : 0;
    __syncthreads();
    for (int o = 128; o > 0; o >>= 1) {
        if (t < o) s[t] += s[t + o];
        __syncthreads();
    }
    if (t == 0) bsum[blockIdx.x] = s[0];
}

__global__ __launch_bounds__(512) void k_boff(const int* __restrict__ bsum, int nb, int* __restrict__ boff)
{
    __shared__ int s[512];
    int t = threadIdx.x;
    int v = (t < nb) ? bsum[t] : 0;
    s[t] = v;
    __syncthreads();
    for (int o = 1; o < 512; o <<= 1) {
        int a = (t >= o) ? s[t - o] : 0;
        __syncthreads();
        s[t] += a;
        __syncthreads();
    }
    if (t < nb) boff[t] = s[t] - v;   // exclusive
}

__global__ __launch_bounds__(256) void k_rowstart(const int* __restrict__ deg, const int* __restrict__ boff,
                                                  int* __restrict__ rs, int n, int total)
{
    __shared__ int s[256];
    int t = threadIdx.x;
    int i = blockIdx.x * 256 + t;
    int v = (i < n) ? deg[i] : 0;
    s[t] = v;
    __syncthreads();
    for (int o = 1; o < 256; o <<= 1) {
        int a = (t >= o) ? s[t - o] : 0;
        __syncthreads();
        s[t] += a;
        __syncthreads();
    }
    if (i < n) rs[i] = boff[blockIdx.x] + s[t] - v;
    if (i == 0) rs[n] = total;
}

__global__ __launch_bounds__(256) void k_scatter(const int* __restrict__ ei, const int* __restrict__ rs,
                                                 int* __restrict__ cursor, int* __restrict__ col, int E)
{
    int e = blockIdx.x * 256 + threadIdx.x;
    if (e < E) {
        int d = ei[E + e];
        int pos = atomicAdd(&cursor[d], 1);
        col[rs[d] + pos] = ei[e];
    }
}

// hsc[v][j] = dinv[v] * sum_k in[v][k] * W[k][j]   (wave-per-node, lane=j)
template <int DIN>
__global__ __launch_bounds__(256) void k_nodemm(const float* __restrict__ in, const float* __restrict__ W,
                                                const float* __restrict__ dinv, float* __restrict__ out, int n)
{
    int lane = threadIdx.x & 63;
    int v = __builtin_amdgcn_readfirstlane(blockIdx.x * 4 + (threadIdx.x >> 6));
    if (v >= n) return;
    const float* row = &in[(size_t)v * DIN];   // wave-uniform -> scalar loads
    float acc = 0.f;
#pragma unroll
    for (int k = 0; k < DIN; ++k) acc = fmaf(row[k], W[k * 64 + lane], acc);
    out[(size_t)v * 64 + lane] = acc * dinv[v];
}

// out[v][j] = f( dinv[v] * (hsc[v][j] + sum_{e: dst=v} hsc[col[e]][j]) + bias[j] )
__global__ __launch_bounds__(256) void k_agg(const float* __restrict__ hsc, const float* __restrict__ dinv,
                                             const int* __restrict__ rs, const int* __restrict__ col,
                                             const float* __restrict__ bias, float* __restrict__ out,
                                             int n, int do_relu)
{
    int lane = threadIdx.x & 63;
    int v = __builtin_amdgcn_readfirstlane(blockIdx.x * 4 + (threadIdx.x >> 6));
    if (v >= n) return;
    float acc = hsc[(size_t)v * 64 + lane];   // self loop
    int i = rs[v], end = rs[v + 1];
    for (; i + 3 < end; i += 4) {
        int s0 = col[i], s1 = col[i + 1], s2 = col[i + 2], s3 = col[i + 3];
        float a0 = hsc[(size_t)s0 * 64 + lane];
        float a1 = hsc[(size_t)s1 * 64 + lane];
        float a2 = hsc[(size_t)s2 * 64 + lane];
        float a3 = hsc[(size_t)s3 * 64 + lane];
        acc += a0; acc += a1; acc += a2; acc += a3;
    }
    for (; i < end; ++i) acc += hsc[(size_t)col[i] * 64 + lane];
    float r = dinv[v] * acc + bias[lane];
    if (do_relu) r = r > 0.f ? r : 0.f;
    out[(size_t)v * 64 + lane] = r;
}

// ---------------------------------------------------------------------------
// MFMA edge MLP. Block = 256 thr = 4 waves; each wave owns 32 edges.
// Layer 1: per wave, D[32 edges][64 hid] = A[32x144] @ Wc1[144x64], bf16 MFMA.
//   A gathered direct from global (h2[src] | h2[dst] | attr), no LDS/barrier.
//   K = 144 = 9 k-steps of 16.  A: row=lane&31, k=(lane>>5)*8+i.
//   B (Wc1) frags in VGPRs: col=lane&31 (+32*nt), same k.  Loaded once/block.
//   C/D: col=lane&31, row=(reg&3)+8*(reg>>2)+4*(lane>>5).
// Layer 2: hid f32 -> LDS [128][68]; 640 (edge,class) dots of 64 from LDS.
// ---------------------------------------------------------------------------
#define HPAD 68

__global__ __launch_bounds__(256) void k_edge_mlp_mfma(
    const float* __restrict__ h2, const float* __restrict__ eattr,
    const int* __restrict__ ei,
    const float* __restrict__ Wc1, const float* __restrict__ bc1,
    const float* __restrict__ Wc2, const float* __restrict__ bc2,
    float* __restrict__ out, int E)
{
    __shared__ float hid[128 * HPAD];   // 34.8 KB
    __shared__ float wc2s[64 * 5];
    __shared__ float bc2s[8];

    const int tid  = threadIdx.x;
    const int w    = tid >> 6;
    const int lane = tid & 63;
    const int r    = lane & 31;   // A row (edge) / B col (hidden j)
    const int kg   = lane >> 5;   // k-group within k-step

    for (int i = tid; i < 320; i += 256) wc2s[i] = Wc2[i];
    if (tid < 5) bc2s[tid] = bc2[tid];

    // ---- Wc1 fragments -> VGPRs (9 ksteps x 2 ntiles x 8 bf16) ----
    bf16x8 bfrag[9][2];
#pragma unroll
    for (int t = 0; t < 9; ++t) {
        const int k0 = t * 16 + kg * 8;
#pragma unroll
        for (int nt = 0; nt < 2; ++nt) {
            const int j = r + nt * 32;
            bf16x8 f;
#pragma unroll
            for (int i = 0; i < 8; ++i) f[i] = f2bf(Wc1[(k0 + i) * 64 + j]);
            bfrag[t][nt] = f;
        }
    }
    const float bias0 = bc1[r];
    const float bias1 = bc1[r + 32];

    // ---- A gather + MFMA ----
    const long eb = (long)blockIdx.x * 128 + w * 32;
    long e = eb + r;
    if (e >= E) e = E - 1;                 // clamp: tile tail (never stored)
    const int s = ei[e];
    const int d = ei[E + e];
    const float* srow = &h2[(size_t)s * 64];
    const float* drow = &h2[(size_t)d * 64];
    const float* arow = &eattr[(size_t)e * 16];

    f32x16 acc0 = {0.f}, acc1 = {0.f};
#pragma unroll
    for (int t = 0; t < 9; ++t) {
        const float* src = (t < 4) ? &srow[t * 16 + kg * 8]
                         : (t < 8) ? &drow[(t - 4) * 16 + kg * 8]
                                   : &arow[kg * 8];
        float4 lo = *(const float4*)src;
        float4 hi = *(const float4*)(src + 4);
        bf16x8 a;
        a[0] = f2bf(lo.x); a[1] = f2bf(lo.y); a[2] = f2bf(lo.z); a[3] = f2bf(lo.w);
        a[4] = f2bf(hi.x); a[5] = f2bf(hi.y); a[6] = f2bf(hi.z); a[7] = f2bf(hi.w);
        acc0 = __builtin_amdgcn_mfma_f32_32x32x16_bf16(a, bfrag[t][0], acc0, 0, 0, 0);
        acc1 = __builtin_amdgcn_mfma_f32_32x32x16_bf16(a, bfrag[t][1], acc1, 0, 0, 0);
    }

    // ---- epilogue layer 1: bias + relu -> LDS ----
#pragma unroll
    for (int reg = 0; reg < 16; ++reg) {
        const int row = (reg & 3) + 8 * (reg >> 2) + 4 * kg;
        float v0 = acc0[reg] + bias0;
        float v1 = acc1[reg] + bias1;
        v0 = v0 > 0.f ? v0 : 0.f;
        v1 = v1 > 0.f ? v1 : 0.f;
        hid[(w * 32 + row) * HPAD + r]      = v0;
        hid[(w * 32 + row) * HPAD + r + 32] = v1;
    }
    __syncthreads();

    // ---- layer 2: 640 (edge,class) items, 64-FMA dots from LDS ----
    const long ebase = (long)blockIdx.x * 128;
#pragma unroll
    for (int it = 0; it < 3; ++it) {
        const int item = it * 256 + tid;
        if (item < 640) {
            const int el = item / 5;
            const int c  = item - el * 5;
            if (ebase + el < E) {
                float o = bc2s[c];
                const float* hrow = &hid[el * HPAD];
#pragma unroll
                for (int k = 0; k < 64; ++k) o = fmaf(hrow[k], wc2s[k * 5 + c], o);
                out[(size_t)(ebase + el) * 5 + c] = o;
            }
        }
    }
}

extern "C" void kernel_launch(void* const* d_in, const int* in_sizes, int n_in,
                              void* d_out, int out_size, void* d_ws, size_t ws_size,
                              hipStream_t stream)
{
    const float* x     = (const float*)d_in[0];
    const int*   ei    = (const int*)d_in[1];
    const float* eattr = (const float*)d_in[2];
    const float* W1    = (const float*)d_in[3];
    const float* b1    = (const float*)d_in[4];
    const float* W2    = (const float*)d_in[5];
    const float* b2    = (const float*)d_in[6];
    const float* Wc1   = (const float*)d_in[7];
    const float* bc1   = (const float*)d_in[8];
    const float* Wc2   = (const float*)d_in[9];
    const float* bc2   = (const float*)d_in[10];
    float* outp = (float*)d_out;

    const int N = in_sizes[0] / 32;
    const int E = in_sizes[1] / 2;

    // ---- carve workspace ----
    size_t off = 0;
    char* base = (char*)d_ws;
    auto carve = [&](size_t bytes) -> void* {
        void* p = base + off;
        off += (bytes + 255) & ~(size_t)255;
        return p;
    };
    int*   degcnt = (int*)carve((size_t)2 * N * 4);   // degcnt + cursor adjacent
    int*   cursor = degcnt + N;
    float* dinv   = (float*)carve((size_t)N * 4);
    int*   rs     = (int*)carve((size_t)(N + 1) * 4);
    int*   bsum   = (int*)carve(512 * 4);
    int*   boff   = (int*)carve(512 * 4);
    int*   col    = (int*)carve((size_t)E * 4);
    float* bufB   = (float*)carve((size_t)N * 64 * 4);
    float* bufA   = outp;   // alias d_out: dead before edge MLP writes it
    (void)ws_size; (void)n_in; (void)out_size;

    const int NB = (N + 255) / 256;
    const int EB = (E + 255) / 256;
    const int NV = (N + 3) / 4;          // wave-per-node kernels, 4 nodes/block
    const int MB = (E + 127) / 128;      // 128 edges per MLP block

    hipMemsetAsync(degcnt, 0, (size_t)2 * N * 4, stream);

    k_hist<<<EB, 256, 0, stream>>>(ei, degcnt, E);
    k_dinv<<<NB, 256, 0, stream>>>(degcnt, dinv, N);
    k_bsum<<<NB, 256, 0, stream>>>(degcnt, N, bsum);
    k_boff<<<1, 512, 0, stream>>>(bsum, NB, boff);
    k_rowstart<<<NB, 256, 0, stream>>>(degcnt, boff, rs, N, E);
    k_scatter<<<EB, 256, 0, stream>>>(ei, rs, cursor, col, E);

    // layer 1
    k_nodemm<32><<<NV, 256, 0, stream>>>(x, W1, dinv, bufA, N);
    k_agg<<<NV, 256, 0, stream>>>(bufA, dinv, rs, col, b1, bufB, N, 1);
    // layer 2
    k_nodemm<64><<<NV, 256, 0, stream>>>(bufB, W2, dinv, bufA, N);
    k_agg<<<NV, 256, 0, stream>>>(bufA, dinv, rs, col, b2, bufB, N, 0);
    // edge MLP (MFMA)
    k_edge_mlp_mfma<<<MB, 256, 0, stream>>>(bufB, eattr, ei, Wc1, bc1, Wc2, bc2, outp, E);
}